// Round 14
// baseline (293.578 us; speedup 1.0000x reference)
//
#include <hip/hip_runtime.h>
#include <math.h>

#define BB 8
#define CC 128
#define NN 2048
#define KK 10
#define TWO_CC 256
#define DEP 12
#define MYS 4            // candidate-range quarters per row (512 each)

typedef __attribute__((ext_vector_type(8))) short bf16x8;
typedef __attribute__((ext_vector_type(4))) float f32x4;

// async global->LDS, 16B per lane; lds dest = wave-uniform base + lane*16
__device__ __forceinline__ void gload16(const void* g, void* l) {
    __builtin_amdgcn_global_load_lds((const __attribute__((address_space(1))) void*)g,
                                     (__attribute__((address_space(3))) void*)l, 16, 0, 0);
}

// round-to-nearest bf16
__device__ __forceinline__ unsigned short rtnbf(float v) {
    unsigned u = __float_as_uint(v);
    return (unsigned short)((u + 0x7FFFu + ((u >> 16) & 1u)) >> 16);
}

// compare-swap keeping the larger value in a (descending order)
__device__ __forceinline__ void csd(unsigned &a, unsigned &b) {
    unsigned hi = a > b ? a : b, lo = a > b ? b : a;
    a = hi; b = lo;
}

// ---------------- fused: transpose + bf16 hi split + f64/f32 norms ----------------
// block: (b, 32-n tile) -> grid 512 = 2/CU (was 1/CU at 64-n). Values of ht/hti identical;
// xx differs only by f64 reassociation (~1e-15 rel), 7 orders below f64 score gaps.
__global__ __launch_bounds__(256) void k_pre(const float* __restrict__ h, float* __restrict__ ht,
                                             unsigned short* __restrict__ hti,
                                             double* __restrict__ xx, float* __restrict__ xxf) {
    __shared__ __align__(16) float tile[128][36];   // row stride 144B (16B-aligned)
    int b = blockIdx.y, n0 = blockIdx.x * 32;
    int t = threadIdx.x;
    const float* hb = h + (size_t)b * CC * NN;
#pragma unroll
    for (int i = 0; i < 4; ++i) {
        int g = t + 256 * i;        // 0..1023 float4 groups
        int c = g >> 3, u = g & 7;
        float4 v = *(const float4*)(hb + (size_t)c * NN + n0 + u * 4);
        *(float4*)(&tile[c][u * 4]) = v;
    }
    __syncthreads();
    int n = t >> 3, cq = t & 7;     // 8 threads/row; thread owns c = cq*4 + j*32 + e
    size_t ob = (size_t)b * NN * CC + (size_t)(n0 + n) * CC;
    double s = 0.0;
#pragma unroll
    for (int j = 0; j < 4; ++j) {
        int c0 = cq * 4 + j * 32;
        float4 w;
        w.x = tile[c0 + 0][n]; w.y = tile[c0 + 1][n];
        w.z = tile[c0 + 2][n]; w.w = tile[c0 + 3][n];
        *(float4*)(ht + ob + c0) = w;
        ushort4 hw;
        hw.x = rtnbf(w.x); hw.y = rtnbf(w.y); hw.z = rtnbf(w.z); hw.w = rtnbf(w.w);
        *(ushort4*)(hti + ob + c0) = hw;
        s += (double)w.x * w.x + (double)w.y * w.y + (double)w.z * w.z + (double)w.w * w.w;
    }
    s += __shfl_xor(s, 1, 64);
    s += __shfl_xor(s, 2, 64);
    s += __shfl_xor(s, 4, 64);      // fixed-order 8-lane tree
    if (cq == 0) {
        xx[b * NN + n0 + n] = s;
        xxf[b * NN + n0 + n] = (float)s;
    }
}

// ---------------- MFMA hi-only screen + packed-key top-12 per (row, quarter) ----------------
// block: 128 thr (2 waves), 32 rows x quarter my. Wave owns 16 rows (one MFMA A-frag).
// LDS: A hi [32][128] bf16 (8KB) + B hi dbuf 2x[16][128] (2x4KB) = 16KB.
// launch_bounds(128,4) -> 8 blocks/CU resident; grid 2048 = 8/CU exact (was 4).
// Key stream, flush batches (64-cand groups) and 16-lane merge are arithmetically
// identical to the 64-row version -> cand bit-identical.
__global__ __launch_bounds__(128, 4) void k_knn(const unsigned short* __restrict__ hti,
                                                const float* __restrict__ xxf,
                                                unsigned* __restrict__ cand) {
    __shared__ __align__(16) char smem[16384];
    int t = threadIdx.x;
    int lane = t & 63, wv = t >> 6;                 // wv 0..1
    int b = blockIdx.z, my = blockIdx.y, n0 = blockIdx.x * 32;

    const unsigned short* h0 = hti + (size_t)b * NN * CC;

    // ---- stage A-tile once (32 rows, 8KB = 512 slots) ----
#pragma unroll
    for (int q = 0; q < 4; ++q) {
        int sidx = q * 128 + t;
        int n = sidx >> 4, ch = sidx & 15;
        gload16(h0 + (size_t)(n0 + n) * CC + ((ch ^ (n & 7)) << 3), smem + sidx * 16);
    }

    auto stageB = [&](int mt, int buf) {
        int m0b = my * 512 + mt * 16;
#pragma unroll
        for (int q = 0; q < 2; ++q) {
            int sidx = q * 128 + t;
            int mr = sidx >> 4, ch = sidx & 15;
            gload16(h0 + (size_t)(m0b + mr) * CC + ((ch ^ (mr & 7)) << 3),
                    smem + 8192 + buf * 4096 + sidx * 16);
        }
    };

    unsigned L[4][DEP];
#pragma unroll
    for (int r = 0; r < 4; ++r)
#pragma unroll
        for (int q = 0; q < DEP; ++q) L[r][q] = 0u;
    unsigned Bt[4][4];

    stageB(0, 0);
    __syncthreads();

    // hoist this wave's A fragments (16 rows x 128 k, hi)
    bf16x8 ahi[4];
    int swz = (lane & 7) << 4;
    {
        int abase = (wv * 16 + (lane & 15)) * 256;
#pragma unroll
        for (int ks = 0; ks < 4; ++ks) {
            int off = (abase + ks * 64 + ((lane >> 4) << 4)) ^ swz;
            ahi[ks] = *(const bf16x8*)(smem + off);
        }
    }

    const float* xb = xxf + b * NN;
    int buf = 0;
    for (int mt = 0; mt < 32; ++mt) {
        if (mt + 1 < 32) stageB(mt + 1, buf ^ 1);
        const char* Bb = smem + 8192 + buf * 4096;
        int m0 = my * 512 + mt * 16;
        {
            float xm = xb[m0 + (lane & 15)];
            f32x4 Cf = {0.f, 0.f, 0.f, 0.f};
            int rb = (lane & 15) * 256;
#pragma unroll
            for (int ks = 0; ks < 4; ++ks) {
                int off = (rb + ks * 64 + ((lane >> 4) << 4)) ^ swz;
                bf16x8 bh = *(const bf16x8*)(Bb + off);
                Cf = __builtin_amdgcn_mfma_f32_16x16x32_bf16(ahi[ks], bh, Cf, 0, 0, 0);
            }
            unsigned invrel = 511u - (unsigned)(mt * 16 + (lane & 15));
#pragma unroll
            for (int r = 0; r < 4; ++r) {
                float v = fmaf(2.f, Cf[r], -xm);
                unsigned u = __float_as_uint(v);
                u ^= (unsigned)((int)u >> 31) | 0x80000000u;
                Bt[r][mt & 3] = (u & 0xFFFFFE00u) | invrel;
            }
        }
        if ((mt & 3) == 3) {
            // flush: exact top-12 of (L[12] ∪ Bt[4]) via bitonic re-sort of 16
#pragma unroll
            for (int r = 0; r < 4; ++r) {
                unsigned s0 = Bt[r][0], s1 = Bt[r][1], s2 = Bt[r][2], s3 = Bt[r][3];
                csd(s0, s1); csd(s2, s3); csd(s0, s2); csd(s1, s3); csd(s1, s2); // desc
                unsigned C[16];
#pragma unroll
                for (int q = 0; q < DEP; ++q) C[q] = L[r][q];
                C[12] = s3; C[13] = s2; C[14] = s1; C[15] = s0;   // asc tail -> bitonic
#pragma unroll
                for (int d = 8; d >= 1; d >>= 1)
#pragma unroll
                    for (int i = 0; i < 16; ++i)
                        if (!(i & d)) csd(C[i], C[i + d]);
#pragma unroll
                for (int q = 0; q < DEP; ++q) L[r][q] = C[q];
            }
        }
        __syncthreads();
        buf ^= 1;
    }

    // merge across the 16 lanes of each row-group: pad lists to 16 with 0-sentinels,
    // register bitonic merge (masks 1,2,4,8); top-12 of the union survives exactly.
#pragma unroll
    for (int r = 0; r < 4; ++r) {
        unsigned T[16];
#pragma unroll
        for (int q = 0; q < DEP; ++q) T[q] = L[r][q];
#pragma unroll
        for (int q = DEP; q < 16; ++q) T[q] = 0u;
#pragma unroll
        for (int rnd = 0; rnd < 4; ++rnd) {
            unsigned C[16];
#pragma unroll
            for (int q = 0; q < 16; ++q) {
                unsigned pv = (unsigned)__shfl_xor((int)T[15 - q], 1 << rnd, 64);
                C[q] = T[q] > pv ? T[q] : pv;
            }
#pragma unroll
            for (int d = 8; d >= 1; d >>= 1)
#pragma unroll
                for (int i = 0; i < 16; ++i)
                    if (!(i & d)) csd(C[i], C[i + d]);
#pragma unroll
            for (int q = 0; q < 16; ++q) T[q] = C[q];
        }
        if ((lane & 15) == 0) {
            int n = n0 + wv * 16 + (lane >> 4) * 4 + r;
            unsigned* op = cand + ((size_t)(b * MYS + my) * NN + n) * DEP;
#pragma unroll
            for (int q = 0; q < DEP; ++q) op[q] = T[q];
        }
    }
}

// ---------------- fused re-score: key-trim 48->16, exact f64 on 16, top-10, mean ----------------
// 4 waves/block, 1 row/wave. Lanes 0..47 load candidates; u32-key rank-by-count trims to the
// screen-top-16 of the union (margin 6 over 10, R5-proven); exact f64 re-rank of those 16;
// mean summed in rank order (identical index set & order -> M bit-identical).
__global__ __launch_bounds__(256) void k_rg(const float* __restrict__ ht, const double* __restrict__ xxg,
                                            const unsigned* __restrict__ cand, float* __restrict__ M) {
    int wv = threadIdx.x >> 6, lane = threadIdx.x & 63;
    int r = blockIdx.x * 4 + wv;
    int b = r >> 11, n = r & (NN - 1);
    const float* base = ht + (size_t)b * NN * CC;

    bool act = lane < MYS * DEP;                     // 48 candidates
    int qr = lane / DEP;                             // quarter 0..3
    unsigned key = 0u;
    int m = 0;
    if (act) {
        key = cand[((size_t)(b * MYS + qr) * NN + n) * DEP + (lane - DEP * qr)];
        m = qr * 512 + 511 - (int)(key & 511u);
    }

    // ---- screen trim: rank active lanes by (key desc, lane asc); only c<48 can hold keys ----
    int krank = 0;
#pragma unroll
    for (int c = 0; c < MYS * DEP; ++c) {
        unsigned kc = (unsigned)__shfl((int)key, c, 64);
        if (kc > key || (kc == key && c < lane)) ++krank;
    }
    int mk = __builtin_amdgcn_ds_permute(krank << 2, m);   // lanes 0..15 = screen-top-16 m's

    bool act16 = lane < 16;
    int m16 = act16 ? mk : n;                        // benign dummy for lanes >=16
    double xxm = xxg[b * NN + m16];

    int cseg = (lane & 7) * 4;                       // this lane's 4-ch unit within each 32-ch block
    double xd[16];
#pragma unroll
    for (int j = 0; j < 4; ++j) {
        float4 xv = *(const float4*)(base + (size_t)n * CC + 32 * j + cseg);
        xd[4 * j + 0] = (double)xv.x; xd[4 * j + 1] = (double)xv.y;
        xd[4 * j + 2] = (double)xv.z; xd[4 * j + 3] = (double)xv.w;
    }

    double dtot = 0.0;
#pragma unroll
    for (int p = 0; p < 2; ++p) {                    // 2 passes x 8 candidates
        int mp = __shfl(m16, p * 8 + (lane >> 3), 64);
        const float* pm = base + (size_t)mp * CC + cseg;
        double a = 0.0;
#pragma unroll
        for (int j = 0; j < 4; ++j) {
            float4 f = *(const float4*)(pm + 32 * j);
            a += xd[4 * j + 0] * (double)f.x + xd[4 * j + 1] * (double)f.y
               + xd[4 * j + 2] * (double)f.z + xd[4 * j + 3] * (double)f.w;
        }
        a += __shfl_xor(a, 1, 64);
        a += __shfl_xor(a, 2, 64);
        a += __shfl_xor(a, 4, 64);                   // 8-lane group sum -> full 128-ch dot
        double got = __shfl(a, (lane & 7) * 8 + (lane >> 3), 64);   // transpose collect
        if ((lane >> 3) == p) dtot = got;            // lane c (<16) holds dot of candidate c
    }

    double sv = act16 ? (2.0 * dtot - xxm) : -1.0e300;
    int si = act16 ? m16 : (0x40000000 + lane);      // unique sentinels

    // exact rank over the 16 survivors under (v desc, idx asc) — distinct m's -> unique ranks.
    int rank = 0;
#pragma unroll
    for (int c = 0; c < 16; ++c) {
        double sc = __shfl(sv, c, 64);
        int ic = __shfl(si, c, 64);
        if ((sc > sv) || (sc == sv && ic < si)) ++rank;
    }
    int mbr = __builtin_amdgcn_ds_permute(rank << 2, m16);   // push m to lane=rank

    float sx = 0.f, sy = 0.f;
#pragma unroll
    for (int rr = 0; rr < 10; ++rr) {                // rank-order summation (as before)
        int mr = __shfl(mbr, rr, 64);
        float2 pm2 = *(const float2*)(base + (size_t)mr * CC + 2 * lane);
        sx += pm2.x; sy += pm2.y;
    }
    float2 o; o.x = sx * (1.f / KK); o.y = sy * (1.f / KK);
    *(float2*)(M + (size_t)r * CC + 2 * lane) = o;
}

// ---------------- y = Wa*M + (Wb-Wa)*h + bias (exact f32 path, float4 LDS reads) ----------------
__global__ __launch_bounds__(256) void k_gemm(const float* __restrict__ M, const float* __restrict__ h,
                                              const float* __restrict__ W, const float* __restrict__ bias,
                                              float* __restrict__ y) {
    __shared__ __align__(16) float Wt[32][68];   // [c][o] transposed W-tile (row start 16B-aligned)
    __shared__ __align__(16) float Xs[32][68];   // [c][n]
    int b = blockIdx.z;
    int o0 = blockIdx.y * 64;
    int n0 = blockIdx.x * 64;
    int tid = threadIdx.x;
    int tx = tid & 15, ty = tid >> 4;
    float acc[4][4] = {};
    const float* Mb = M + (size_t)b * NN * CC;
    const float* hb = h + (size_t)b * CC * NN;

    for (int c0 = 0; c0 < CC; c0 += 32) {
        for (int i = tid; i < 64 * 32; i += 256) {
            int c = i & 31, o = i >> 5;
            Wt[c][o] = W[(size_t)(o0 + o) * TWO_CC + c0 + c];
        }
        for (int i = tid; i < 64 * 32; i += 256) {
            int c = i & 31, nn = i >> 5;
            Xs[c][nn] = Mb[(size_t)(n0 + nn) * CC + c0 + c];
        }
        __syncthreads();
        for (int c = 0; c < 32; ++c) {
            float4 a4 = *(const float4*)&Wt[c][ty * 4];
            float4 b4 = *(const float4*)&Xs[c][tx * 4];
            float a[4] = {a4.x, a4.y, a4.z, a4.w};
            float bb[4] = {b4.x, b4.y, b4.z, b4.w};
#pragma unroll
            for (int i2 = 0; i2 < 4; ++i2)
#pragma unroll
                for (int j = 0; j < 4; ++j) acc[i2][j] += a[i2] * bb[j];
        }
        __syncthreads();
    }
    for (int c0 = 0; c0 < CC; c0 += 32) {
        for (int i = tid; i < 64 * 32; i += 256) {
            int c = i & 31, o = i >> 5;
            const float* wr = W + (size_t)(o0 + o) * TWO_CC;
            Wt[c][o] = wr[CC + c0 + c] - wr[c0 + c];
        }
        for (int i = tid; i < 64 * 32; i += 256) {
            int nn = i & 63, c = i >> 6;
            Xs[c][nn] = hb[(size_t)(c0 + c) * NN + n0 + nn];
        }
        __syncthreads();
        for (int c = 0; c < 32; ++c) {
            float4 a4 = *(const float4*)&Wt[c][ty * 4];
            float4 b4 = *(const float4*)&Xs[c][tx * 4];
            float a[4] = {a4.x, a4.y, a4.z, a4.w};
            float bb[4] = {b4.x, b4.y, b4.z, b4.w};
#pragma unroll
            for (int i2 = 0; i2 < 4; ++i2)
#pragma unroll
                for (int j = 0; j < 4; ++j) acc[i2][j] += a[i2] * bb[j];
        }
        __syncthreads();
    }
#pragma unroll
    for (int i2 = 0; i2 < 4; ++i2) {
        int o = o0 + ty * 4 + i2;
        float bv = bias[o];
#pragma unroll
        for (int j = 0; j < 4; ++j)
            y[((size_t)b * CC + o) * NN + n0 + tx * 4 + j] = acc[i2][j] + bv;
    }
}

// ---------------- per-(b,o) mean/var(ddof=1), relu, optional residual ----------------
__global__ __launch_bounds__(256) void k_norm(const float* __restrict__ y, const float* __restrict__ res,
                                              float* __restrict__ out, int add_res) {
    int bo = blockIdx.x;
    const float* row = y + (size_t)bo * NN;
    float s = 0.f, s2 = 0.f;
    for (int n = threadIdx.x; n < NN; n += 256) {
        float v = row[n];
        s += v;
        s2 += v * v;
    }
#pragma unroll
    for (int off = 32; off > 0; off >>= 1) {
        s += __shfl_down(s, off, 64);
        s2 += __shfl_down(s2, off, 64);
    }
    __shared__ float ss[4], ss2[4];
    int wave = threadIdx.x >> 6, lane = threadIdx.x & 63;
    if (lane == 0) { ss[wave] = s; ss2[wave] = s2; }
    __syncthreads();
    if (threadIdx.x == 0) {
        float S = ss[0] + ss[1] + ss[2] + ss[3];
        float S2 = ss2[0] + ss2[1] + ss2[2] + ss2[3];
        float mean = S * (1.f / NN);
        float var = (S2 - S * mean) * (1.f / (NN - 1));
        ss[0] = mean;
        ss2[0] = rsqrtf(var + 1e-3f);
    }
    __syncthreads();
    float mean = ss[0], inv = ss2[0];
    for (int n = threadIdx.x; n < NN; n += 256) {
        float v = (row[n] - mean) * inv;
        v = fmaxf(v, 0.f);
        if (add_res) v += res[(size_t)bo * NN + n];
        out[(size_t)bo * NN + n] = v;
    }
}

extern "C" void kernel_launch(void* const* d_in, const int* in_sizes, int n_in,
                              void* d_out, int out_size, void* d_ws, size_t ws_size,
                              hipStream_t stream) {
    const float* x  = (const float*)d_in[0];
    const float* W1 = (const float*)d_in[1];
    const float* b1 = (const float*)d_in[2];
    const float* W2 = (const float*)d_in[3];
    const float* b2 = (const float*)d_in[4];
    float* out = (float*)d_out;

    char* p = (char*)d_ws;
    double* xx = (double*)p;   p += (size_t)BB * NN * 8;          // 128 KB
    float* xxf = (float*)p;    p += (size_t)BB * NN * 4;          // 64 KB
    float* ht = (float*)p;     p += (size_t)BB * NN * CC * 4;     // 8 MB f32 transposed
    float* Mw = (float*)p;     p += (size_t)BB * NN * CC * 4;     // 8 MB neighbor-mean (f32)
    float* y  = (float*)p;     p += (size_t)BB * CC * NN * 4;     // 8 MB
    float* h1 = (float*)p;                                        // 8 MB

    // overlays (lifetime-disjoint):
    // hti (4 MB, screen input) lives in M's region — consumed by k_knn before k_rg writes M.
    // cand (3 MB) lives in y's region — consumed by k_rg before k_gemm writes y.
    unsigned short* hti = (unsigned short*)Mw;
    unsigned* cand = (unsigned*)y;

    auto layer = [&](const float* hin, const float* Wt, const float* bt, float* hout, int add_res) {
        hipLaunchKernelGGL(k_pre, dim3(NN / 32, BB), dim3(256), 0, stream, hin, ht, hti, xx, xxf);
        hipLaunchKernelGGL(k_knn, dim3(NN / 32, MYS, BB), dim3(128), 0, stream, hti, xxf, cand);
        hipLaunchKernelGGL(k_rg, dim3(BB * NN / 4), dim3(256), 0, stream, ht, xx, cand, Mw);
        hipLaunchKernelGGL(k_gemm, dim3(NN / 64, CC / 64, BB), dim3(256), 0, stream, Mw, hin, Wt, bt, y);
        hipLaunchKernelGGL(k_norm, dim3(BB * CC), dim3(256), 0, stream, y, x, hout, add_res);
    };

    layer(x, W1, b1, h1, 0);
    layer(h1, W2, b2, out, 1);
}

// Round 15
// 283.635 us; speedup vs baseline: 1.0351x; 1.0351x over previous
//
#include <hip/hip_runtime.h>
#include <math.h>

#define BB 8
#define CC 128
#define NN 2048
#define KK 10
#define TWO_CC 256
#define DEP 12
#define MYS 4            // candidate-range quarters per row (512 each)

typedef __attribute__((ext_vector_type(8))) short bf16x8;
typedef __attribute__((ext_vector_type(4))) float f32x4;

// async global->LDS, 16B per lane; lds dest = wave-uniform base + lane*16
__device__ __forceinline__ void gload16(const void* g, void* l) {
    __builtin_amdgcn_global_load_lds((const __attribute__((address_space(1))) void*)g,
                                     (__attribute__((address_space(3))) void*)l, 16, 0, 0);
}

// round-to-nearest bf16
__device__ __forceinline__ unsigned short rtnbf(float v) {
    unsigned u = __float_as_uint(v);
    return (unsigned short)((u + 0x7FFFu + ((u >> 16) & 1u)) >> 16);
}

// compare-swap keeping the larger value in a (descending order)
__device__ __forceinline__ void csd(unsigned &a, unsigned &b) {
    unsigned hi = a > b ? a : b, lo = a > b ? b : a;
    a = hi; b = lo;
}

// ---------------- fused: transpose + bf16 hi split + f64/f32 norms ----------------
// block: (b, 32-n tile) -> grid 512 = 2/CU. Values of ht/hti identical to the f32 source;
// xx differs only by f64 reassociation (~1e-15 rel), 7 orders below f64 score gaps.
__global__ __launch_bounds__(256) void k_pre(const float* __restrict__ h, float* __restrict__ ht,
                                             unsigned short* __restrict__ hti,
                                             double* __restrict__ xx, float* __restrict__ xxf) {
    __shared__ __align__(16) float tile[128][36];   // row stride 144B (16B-aligned)
    int b = blockIdx.y, n0 = blockIdx.x * 32;
    int t = threadIdx.x;
    const float* hb = h + (size_t)b * CC * NN;
#pragma unroll
    for (int i = 0; i < 4; ++i) {
        int g = t + 256 * i;        // 0..1023 float4 groups
        int c = g >> 3, u = g & 7;
        float4 v = *(const float4*)(hb + (size_t)c * NN + n0 + u * 4);
        *(float4*)(&tile[c][u * 4]) = v;
    }
    __syncthreads();
    int n = t >> 3, cq = t & 7;     // 8 threads/row; thread owns c = cq*4 + j*32 + e
    size_t ob = (size_t)b * NN * CC + (size_t)(n0 + n) * CC;
    double s = 0.0;
#pragma unroll
    for (int j = 0; j < 4; ++j) {
        int c0 = cq * 4 + j * 32;
        float4 w;
        w.x = tile[c0 + 0][n]; w.y = tile[c0 + 1][n];
        w.z = tile[c0 + 2][n]; w.w = tile[c0 + 3][n];
        *(float4*)(ht + ob + c0) = w;
        ushort4 hw;
        hw.x = rtnbf(w.x); hw.y = rtnbf(w.y); hw.z = rtnbf(w.z); hw.w = rtnbf(w.w);
        *(ushort4*)(hti + ob + c0) = hw;
        s += (double)w.x * w.x + (double)w.y * w.y + (double)w.z * w.z + (double)w.w * w.w;
    }
    s += __shfl_xor(s, 1, 64);
    s += __shfl_xor(s, 2, 64);
    s += __shfl_xor(s, 4, 64);      // fixed-order 8-lane tree
    if (cq == 0) {
        xx[b * NN + n0 + n] = s;
        xxf[b * NN + n0 + n] = (float)s;
    }
}

// ---------------- MFMA hi-only screen + packed-key top-12 per (row, quarter) ----------------
// block: 256 thr (4 waves), 64 rows x quarter my (512 cands). Wave owns 16 rows.
// LDS: A hi [64][128] bf16 (16KB) + B hi dbuf 2x[32][128] (2x8KB) = 32KB -> 4 blocks/CU,
// grid 1024 = exact fill. XOR-swizzle ((row&7)<<4) on GLOBAL source and ds_read (both-sides).
// Selection: batched bitonic merge (flush every 64 candidates) — exact top-12, R13-proven.
__global__ __launch_bounds__(256, 4) void k_knn(const unsigned short* __restrict__ hti,
                                                const float* __restrict__ xxf,
                                                unsigned* __restrict__ cand) {
    __shared__ __align__(16) char smem[32768];
    int t = threadIdx.x;
    int lane = t & 63, wv = t >> 6;
    int b = blockIdx.z, my = blockIdx.y, n0 = blockIdx.x * 64;

    const unsigned short* h0 = hti + (size_t)b * NN * CC;

    // ---- stage A-tile once (hi only, 16KB = 1024 slots) ----
#pragma unroll
    for (int q = 0; q < 4; ++q) {
        int sidx = q * 256 + wv * 64 + lane;
        int n = sidx >> 4, ch = sidx & 15;
        gload16(h0 + (size_t)(n0 + n) * CC + ((ch ^ (n & 7)) << 3),
                smem + (q * 256 + wv * 64) * 16);
    }

    auto stageB = [&](int mt, int buf) {
        int m0b = my * 512 + mt * 32;
#pragma unroll
        for (int q = 0; q < 2; ++q) {
            int sidx = q * 256 + wv * 64 + lane;
            int mr = sidx >> 4, ch = sidx & 15;
            gload16(h0 + (size_t)(m0b + mr) * CC + ((ch ^ (mr & 7)) << 3),
                    smem + 16384 + buf * 8192 + (q * 256 + wv * 64) * 16);
        }
    };

    unsigned L[4][DEP];
#pragma unroll
    for (int r = 0; r < 4; ++r)
#pragma unroll
        for (int q = 0; q < DEP; ++q) L[r][q] = 0u;
    unsigned Bt[4][4];

    stageB(0, 0);
    __syncthreads();

    // hoist this wave's A fragments (16 rows x 128 k, hi)
    bf16x8 ahi[4];
    int swz = (lane & 7) << 4;
    {
        int abase = (wv * 16 + (lane & 15)) * 256;
#pragma unroll
        for (int ks = 0; ks < 4; ++ks) {
            int off = (abase + ks * 64 + ((lane >> 4) << 4)) ^ swz;
            ahi[ks] = *(const bf16x8*)(smem + off);
        }
    }

    const float* xb = xxf + b * NN;
    int buf = 0;
    for (int mt = 0; mt < 16; ++mt) {
        if (mt + 1 < 16) stageB(mt + 1, buf ^ 1);
        const char* Bb = smem + 16384 + buf * 8192;
        int m0 = my * 512 + mt * 32;
#pragma unroll
        for (int cs = 0; cs < 2; ++cs) {
            float xm = xb[m0 + cs * 16 + (lane & 15)];
            f32x4 Cf = {0.f, 0.f, 0.f, 0.f};
            int rb = (cs * 16 + (lane & 15)) * 256;
#pragma unroll
            for (int ks = 0; ks < 4; ++ks) {
                int off = (rb + ks * 64 + ((lane >> 4) << 4)) ^ swz;
                bf16x8 bh = *(const bf16x8*)(Bb + off);
                Cf = __builtin_amdgcn_mfma_f32_16x16x32_bf16(ahi[ks], bh, Cf, 0, 0, 0);
            }
            unsigned invrel = 511u - (unsigned)(mt * 32 + cs * 16 + (lane & 15));
#pragma unroll
            for (int r = 0; r < 4; ++r) {
                float v = fmaf(2.f, Cf[r], -xm);
                unsigned u = __float_as_uint(v);
                u ^= (unsigned)((int)u >> 31) | 0x80000000u;
                Bt[r][(mt & 1) * 2 + cs] = (u & 0xFFFFFE00u) | invrel;
            }
        }
        if (mt & 1) {
            // flush: exact top-12 of (L[12] ∪ Bt[4]) via bitonic re-sort of 16
#pragma unroll
            for (int r = 0; r < 4; ++r) {
                unsigned s0 = Bt[r][0], s1 = Bt[r][1], s2 = Bt[r][2], s3 = Bt[r][3];
                csd(s0, s1); csd(s2, s3); csd(s0, s2); csd(s1, s3); csd(s1, s2); // desc
                unsigned C[16];
#pragma unroll
                for (int q = 0; q < DEP; ++q) C[q] = L[r][q];
                C[12] = s3; C[13] = s2; C[14] = s1; C[15] = s0;   // asc tail -> bitonic
#pragma unroll
                for (int d = 8; d >= 1; d >>= 1)
#pragma unroll
                    for (int i = 0; i < 16; ++i)
                        if (!(i & d)) csd(C[i], C[i + d]);
#pragma unroll
                for (int q = 0; q < DEP; ++q) L[r][q] = C[q];
            }
        }
        __syncthreads();
        buf ^= 1;
    }

    // merge across the 16 lanes of each row-group: pad lists to 16 with 0-sentinels,
    // register bitonic merge (masks 1,2,4,8); top-12 of the union survives exactly.
#pragma unroll
    for (int r = 0; r < 4; ++r) {
        unsigned T[16];
#pragma unroll
        for (int q = 0; q < DEP; ++q) T[q] = L[r][q];
#pragma unroll
        for (int q = DEP; q < 16; ++q) T[q] = 0u;
#pragma unroll
        for (int rnd = 0; rnd < 4; ++rnd) {
            unsigned C[16];
#pragma unroll
            for (int q = 0; q < 16; ++q) {
                unsigned pv = (unsigned)__shfl_xor((int)T[15 - q], 1 << rnd, 64);
                C[q] = T[q] > pv ? T[q] : pv;
            }
#pragma unroll
            for (int d = 8; d >= 1; d >>= 1)
#pragma unroll
                for (int i = 0; i < 16; ++i)
                    if (!(i & d)) csd(C[i], C[i + d]);
#pragma unroll
            for (int q = 0; q < 16; ++q) T[q] = C[q];
        }
        if ((lane & 15) == 0) {
            int n = n0 + wv * 16 + (lane >> 4) * 4 + r;
            unsigned* op = cand + ((size_t)(b * MYS + my) * NN + n) * DEP;
#pragma unroll
            for (int q = 0; q < DEP; ++q) op[q] = T[q];
        }
    }
}

// ---------------- fused re-score: key-trim 48->16, exact f64 on 16, top-10, mean ----------------
// 4 waves/block, 1 row/wave. Lanes 0..47 load candidates; u32-key rank-by-count trims to the
// screen-top-16 of the union (margin 6 over 10, R5-proven); exact f64 re-rank of those 16;
// mean summed in rank order (identical index set & order -> M bit-identical).
__global__ __launch_bounds__(256) void k_rg(const float* __restrict__ ht, const double* __restrict__ xxg,
                                            const unsigned* __restrict__ cand, float* __restrict__ M) {
    int wv = threadIdx.x >> 6, lane = threadIdx.x & 63;
    int r = blockIdx.x * 4 + wv;
    int b = r >> 11, n = r & (NN - 1);
    const float* base = ht + (size_t)b * NN * CC;

    bool act = lane < MYS * DEP;                     // 48 candidates
    int qr = lane / DEP;                             // quarter 0..3
    unsigned key = 0u;
    int m = 0;
    if (act) {
        key = cand[((size_t)(b * MYS + qr) * NN + n) * DEP + (lane - DEP * qr)];
        m = qr * 512 + 511 - (int)(key & 511u);
    }

    // ---- screen trim: rank active lanes by (key desc, lane asc); only c<48 can hold keys ----
    int krank = 0;
#pragma unroll
    for (int c = 0; c < MYS * DEP; ++c) {
        unsigned kc = (unsigned)__shfl((int)key, c, 64);
        if (kc > key || (kc == key && c < lane)) ++krank;
    }
    int mk = __builtin_amdgcn_ds_permute(krank << 2, m);   // lanes 0..15 = screen-top-16 m's

    bool act16 = lane < 16;
    int m16 = act16 ? mk : n;                        // benign dummy for lanes >=16
    double xxm = xxg[b * NN + m16];

    int cseg = (lane & 7) * 4;                       // this lane's 4-ch unit within each 32-ch block
    double xd[16];
#pragma unroll
    for (int j = 0; j < 4; ++j) {
        float4 xv = *(const float4*)(base + (size_t)n * CC + 32 * j + cseg);
        xd[4 * j + 0] = (double)xv.x; xd[4 * j + 1] = (double)xv.y;
        xd[4 * j + 2] = (double)xv.z; xd[4 * j + 3] = (double)xv.w;
    }

    double dtot = 0.0;
#pragma unroll
    for (int p = 0; p < 2; ++p) {                    // 2 passes x 8 candidates
        int mp = __shfl(m16, p * 8 + (lane >> 3), 64);
        const float* pm = base + (size_t)mp * CC + cseg;
        double a = 0.0;
#pragma unroll
        for (int j = 0; j < 4; ++j) {
            float4 f = *(const float4*)(pm + 32 * j);
            a += xd[4 * j + 0] * (double)f.x + xd[4 * j + 1] * (double)f.y
               + xd[4 * j + 2] * (double)f.z + xd[4 * j + 3] * (double)f.w;
        }
        a += __shfl_xor(a, 1, 64);
        a += __shfl_xor(a, 2, 64);
        a += __shfl_xor(a, 4, 64);                   // 8-lane group sum -> full 128-ch dot
        double got = __shfl(a, (lane & 7) * 8 + (lane >> 3), 64);   // transpose collect
        if ((lane >> 3) == p) dtot = got;            // lane c (<16) holds dot of candidate c
    }

    double sv = act16 ? (2.0 * dtot - xxm) : -1.0e300;
    int si = act16 ? m16 : (0x40000000 + lane);      // unique sentinels

    // exact rank over the 16 survivors under (v desc, idx asc) — distinct m's -> unique ranks.
    int rank = 0;
#pragma unroll
    for (int c = 0; c < 16; ++c) {
        double sc = __shfl(sv, c, 64);
        int ic = __shfl(si, c, 64);
        if ((sc > sv) || (sc == sv && ic < si)) ++rank;
    }
    int mbr = __builtin_amdgcn_ds_permute(rank << 2, m16);   // push m to lane=rank

    float sx = 0.f, sy = 0.f;
#pragma unroll
    for (int rr = 0; rr < 10; ++rr) {                // rank-order summation (as before)
        int mr = __shfl(mbr, rr, 64);
        float2 pm2 = *(const float2*)(base + (size_t)mr * CC + 2 * lane);
        sx += pm2.x; sy += pm2.y;
    }
    float2 o; o.x = sx * (1.f / KK); o.y = sy * (1.f / KK);
    *(float2*)(M + (size_t)r * CC + 2 * lane) = o;
}

// ---------------- y = Wa*M + (Wb-Wa)*h + bias (exact f32, o-tile 32 x n-tile 64) ----------------
// grid (NN/64, CC/32, BB) = 1024 blocks = 4/CU (was 2/CU at 64x64). Per-output accumulation
// sequence (c ascending within 32-chunks, chunks in order, M-phase then h-phase) unchanged
// -> y bit-identical.
__global__ __launch_bounds__(256) void k_gemm(const float* __restrict__ M, const float* __restrict__ h,
                                              const float* __restrict__ W, const float* __restrict__ bias,
                                              float* __restrict__ y) {
    __shared__ __align__(16) float Wt[32][36];   // [c][o] transposed W-tile
    __shared__ __align__(16) float Xs[32][68];   // [c][n]
    int b = blockIdx.z;
    int o0 = blockIdx.y * 32;
    int n0 = blockIdx.x * 64;
    int tid = threadIdx.x;
    int tx = tid & 15, ty = tid >> 4;            // tx: 4 n each (64), ty: 2 o each (32)
    float acc[2][4] = {};
    const float* Mb = M + (size_t)b * NN * CC;
    const float* hb = h + (size_t)b * CC * NN;

    for (int c0 = 0; c0 < CC; c0 += 32) {
        for (int i = tid; i < 32 * 32; i += 256) {
            int c = i & 31, o = i >> 5;
            Wt[c][o] = W[(size_t)(o0 + o) * TWO_CC + c0 + c];
        }
        for (int i = tid; i < 64 * 32; i += 256) {
            int c = i & 31, nn = i >> 5;
            Xs[c][nn] = Mb[(size_t)(n0 + nn) * CC + c0 + c];
        }
        __syncthreads();
        for (int c = 0; c < 32; ++c) {
            float2 a2 = *(const float2*)&Wt[c][ty * 2];
            float4 b4 = *(const float4*)&Xs[c][tx * 4];
            float a[2] = {a2.x, a2.y};
            float bb[4] = {b4.x, b4.y, b4.z, b4.w};
#pragma unroll
            for (int i2 = 0; i2 < 2; ++i2)
#pragma unroll
                for (int j = 0; j < 4; ++j) acc[i2][j] += a[i2] * bb[j];
        }
        __syncthreads();
    }
    for (int c0 = 0; c0 < CC; c0 += 32) {
        for (int i = tid; i < 32 * 32; i += 256) {
            int c = i & 31, o = i >> 5;
            const float* wr = W + (size_t)(o0 + o) * TWO_CC;
            Wt[c][o] = wr[CC + c0 + c] - wr[c0 + c];
        }
        for (int i = tid; i < 64 * 32; i += 256) {
            int nn = i & 63, c = i >> 6;
            Xs[c][nn] = hb[(size_t)(c0 + c) * NN + n0 + nn];
        }
        __syncthreads();
        for (int c = 0; c < 32; ++c) {
            float2 a2 = *(const float2*)&Wt[c][ty * 2];
            float4 b4 = *(const float4*)&Xs[c][tx * 4];
            float a[2] = {a2.x, a2.y};
            float bb[4] = {b4.x, b4.y, b4.z, b4.w};
#pragma unroll
            for (int i2 = 0; i2 < 2; ++i2)
#pragma unroll
                for (int j = 0; j < 4; ++j) acc[i2][j] += a[i2] * bb[j];
        }
        __syncthreads();
    }
#pragma unroll
    for (int i2 = 0; i2 < 2; ++i2) {
        int o = o0 + ty * 2 + i2;
        float bv = bias[o];
#pragma unroll
        for (int j = 0; j < 4; ++j)
            y[((size_t)b * CC + o) * NN + n0 + tx * 4 + j] = acc[i2][j] + bv;
    }
}

// ---------------- per-(b,o) mean/var(ddof=1), relu, optional residual — single-pass ----------------
// Row loaded once into registers (same strided order as before -> stats bit-identical),
// normalized from registers (no second global read).
__global__ __launch_bounds__(256) void k_norm(const float* __restrict__ y, const float* __restrict__ res,
                                              float* __restrict__ out, int add_res) {
    int bo = blockIdx.x;
    const float* row = y + (size_t)bo * NN;
    float v[8];
    float s = 0.f, s2 = 0.f;
#pragma unroll
    for (int i = 0; i < 8; ++i) {
        v[i] = row[threadIdx.x + 256 * i];
        s += v[i];
        s2 += v[i] * v[i];
    }
#pragma unroll
    for (int off = 32; off > 0; off >>= 1) {
        s += __shfl_down(s, off, 64);
        s2 += __shfl_down(s2, off, 64);
    }
    __shared__ float ss[4], ss2[4];
    int wave = threadIdx.x >> 6, lane = threadIdx.x & 63;
    if (lane == 0) { ss[wave] = s; ss2[wave] = s2; }
    __syncthreads();
    if (threadIdx.x == 0) {
        float S = ss[0] + ss[1] + ss[2] + ss[3];
        float S2 = ss2[0] + ss2[1] + ss2[2] + ss2[3];
        float mean = S * (1.f / NN);
        float var = (S2 - S * mean) * (1.f / (NN - 1));
        ss[0] = mean;
        ss2[0] = rsqrtf(var + 1e-3f);
    }
    __syncthreads();
    float mean = ss[0], inv = ss2[0];
#pragma unroll
    for (int i = 0; i < 8; ++i) {
        int n = threadIdx.x + 256 * i;
        float w = (v[i] - mean) * inv;
        w = fmaxf(w, 0.f);
        if (add_res) w += res[(size_t)bo * NN + n];
        out[(size_t)bo * NN + n] = w;
    }
}

extern "C" void kernel_launch(void* const* d_in, const int* in_sizes, int n_in,
                              void* d_out, int out_size, void* d_ws, size_t ws_size,
                              hipStream_t stream) {
    const float* x  = (const float*)d_in[0];
    const float* W1 = (const float*)d_in[1];
    const float* b1 = (const float*)d_in[2];
    const float* W2 = (const float*)d_in[3];
    const float* b2 = (const float*)d_in[4];
    float* out = (float*)d_out;

    char* p = (char*)d_ws;
    double* xx = (double*)p;   p += (size_t)BB * NN * 8;          // 128 KB
    float* xxf = (float*)p;    p += (size_t)BB * NN * 4;          // 64 KB
    float* ht = (float*)p;     p += (size_t)BB * NN * CC * 4;     // 8 MB f32 transposed
    float* Mw = (float*)p;     p += (size_t)BB * NN * CC * 4;     // 8 MB neighbor-mean (f32)
    float* y  = (float*)p;     p += (size_t)BB * CC * NN * 4;     // 8 MB
    float* h1 = (float*)p;                                        // 8 MB

    // overlays (lifetime-disjoint):
    // hti (4 MB, screen input) lives in M's region — consumed by k_knn before k_rg writes M.
    // cand (3 MB) lives in y's region — consumed by k_rg before k_gemm writes y.
    unsigned short* hti = (unsigned short*)Mw;
    unsigned* cand = (unsigned*)y;

    auto layer = [&](const float* hin, const float* Wt, const float* bt, float* hout, int add_res) {
        hipLaunchKernelGGL(k_pre, dim3(NN / 32, BB), dim3(256), 0, stream, hin, ht, hti, xx, xxf);
        hipLaunchKernelGGL(k_knn, dim3(NN / 64, MYS, BB), dim3(256), 0, stream, hti, xxf, cand);
        hipLaunchKernelGGL(k_rg, dim3(BB * NN / 4), dim3(256), 0, stream, ht, xx, cand, Mw);
        hipLaunchKernelGGL(k_gemm, dim3(NN / 64, CC / 32, BB), dim3(256), 0, stream, Mw, hin, Wt, bt, y);
        hipLaunchKernelGGL(k_norm, dim3(BB * CC), dim3(256), 0, stream, y, x, hout, add_res);
    };

    layer(x, W1, b1, h1, 0);
    layer(h1, W2, b2, out, 1);
}